// Round 1
// baseline (24241.177 us; speedup 1.0000x reference)
//
#include <hip/hip_runtime.h>

#define N_USERS 100000
#define N_ITEMS 50000
#define NTOT    150000        // N_USERS + N_ITEMS
#define E       128
#define NNZ     4800000
#define BATCH   4096
#define NL      3
#define ROWS_PER_BLOCK 32

// ---------------------------------------------------------------------------
// Copy user_emb / item_emb into the working "ego" buffer A (float4 vectorized)
__global__ __launch_bounds__(256) void init_ego(const float* __restrict__ ue,
                                                const float* __restrict__ ie,
                                                float* __restrict__ A) {
    long long i = (long long)blockIdx.x * blockDim.x + threadIdx.x;  // float4 idx
    const long long nU   = (long long)N_USERS * E / 4;
    const long long nTot = (long long)NTOT * E / 4;
    if (i < nU)        ((float4*)A)[i] = ((const float4*)ue)[i];
    else if (i < nTot) ((float4*)A)[i] = ((const float4*)ie)[i - nU];
}

// ---------------------------------------------------------------------------
// SpMM: out[row] += val * x[col]  (atomic scatter). One wave (64 lanes) per
// edge; each lane handles 2 consecutive floats of the 128-wide row.
__global__ __launch_bounds__(256) void spmm_atomic(const int* __restrict__ row,
                                                   const int* __restrict__ col,
                                                   const float* __restrict__ val,
                                                   const float* __restrict__ x,
                                                   float* __restrict__ out) {
    const int wave   = (blockIdx.x * blockDim.x + threadIdx.x) >> 6;
    const int lane   = threadIdx.x & 63;
    const int nwaves = gridDim.x * (blockDim.x >> 6);
    for (int e = wave; e < NNZ; e += nwaves) {
        const int   r = row[e];
        const int   c = col[e];
        const float v = val[e];
        const float2 xv = ((const float2*)(x + (size_t)c * E))[lane];
        float* o = out + (size_t)r * E + lane * 2;
        unsafeAtomicAdd(o,     v * xv.x);
        unsafeAtomicAdd(o + 1, v * xv.y);
    }
}

// ---------------------------------------------------------------------------
// ego = concat(Bp, Cd) @ W[k] + bias[k]
// Block = 128 threads (one per output column j), ROWS_PER_BLOCK rows per block.
// For each i: one coalesced W-column-row load, broadcast x from LDS, 32 FMAs.
__global__ __launch_bounds__(128) void linear_kernel(const float* __restrict__ Bp,
                                                     const float* __restrict__ Cd,
                                                     const float* __restrict__ Wk,
                                                     const float* __restrict__ bk,
                                                     float* __restrict__ out) {
    __shared__ float sB[ROWS_PER_BLOCK][E];
    __shared__ float sC[ROWS_PER_BLOCK][E];
    const int j  = threadIdx.x;              // output column 0..127
    const int r0 = blockIdx.x * ROWS_PER_BLOCK;

    // stage 32 rows of Bp and Cd (clamped for tail block)
    #pragma unroll
    for (int r = 0; r < ROWS_PER_BLOCK; ++r) {
        int rr = r0 + r; if (rr >= NTOT) rr = NTOT - 1;
        sB[r][j] = Bp[(size_t)rr * E + j];
        sC[r][j] = Cd[(size_t)rr * E + j];
    }
    __syncthreads();

    float acc[ROWS_PER_BLOCK];
    const float bj = bk[j];
    #pragma unroll
    for (int r = 0; r < ROWS_PER_BLOCK; ++r) acc[r] = bj;

    #pragma unroll 4
    for (int i = 0; i < E; ++i) {
        const float w = Wk[(size_t)i * E + j];          // top half of W
        #pragma unroll
        for (int r = 0; r < ROWS_PER_BLOCK; ++r) acc[r] = fmaf(sB[r][i], w, acc[r]);
    }
    #pragma unroll 4
    for (int i = 0; i < E; ++i) {
        const float w = Wk[(size_t)(E + i) * E + j];    // bottom half of W
        #pragma unroll
        for (int r = 0; r < ROWS_PER_BLOCK; ++r) acc[r] = fmaf(sC[r][i], w, acc[r]);
    }

    #pragma unroll
    for (int r = 0; r < ROWS_PER_BLOCK; ++r) {
        const int rr = r0 + r;
        if (rr < NTOT) out[(size_t)rr * E + j] = acc[r];
    }
}

// ---------------------------------------------------------------------------
// Gather final embeddings for the lookup batch.
__global__ __launch_bounds__(256) void gather_out(const float* __restrict__ A,
                                                  const int* __restrict__ users,
                                                  const int* __restrict__ items,
                                                  float* __restrict__ out) {
    const int t = blockIdx.x * blockDim.x + threadIdx.x;   // 0 .. 2*BATCH*E-1
    if (t >= 2 * BATCH * E) return;
    const int j = t & (E - 1);
    const int b = t >> 7;
    if (b < BATCH) {
        out[t] = A[(size_t)users[b] * E + j];
    } else {
        const int bb = b - BATCH;
        out[t] = A[(size_t)(N_USERS + items[bb]) * E + j];
    }
}

// ---------------------------------------------------------------------------
extern "C" void kernel_launch(void* const* d_in, const int* in_sizes, int n_in,
                              void* d_out, int out_size, void* d_ws, size_t ws_size,
                              hipStream_t stream) {
    const float* user_emb = (const float*)d_in[0];
    const float* item_emb = (const float*)d_in[1];
    const float* adj_val  = (const float*)d_in[2];
    const float* hp_val   = (const float*)d_in[3];
    const float* W        = (const float*)d_in[4];
    const float* bias     = (const float*)d_in[5];
    const int*   adj_row  = (const int*)d_in[6];
    const int*   adj_col  = (const int*)d_in[7];
    const int*   hp_row   = (const int*)d_in[8];
    const int*   hp_col   = (const int*)d_in[9];
    const int*   users    = (const int*)d_in[10];
    const int*   items    = (const int*)d_in[11];
    float* out = (float*)d_out;

    float* A  = (float*)d_ws;                 // ego / linear output
    float* Bp = A  + (size_t)NTOT * E;        // low-pass spmm output
    float* Cd = Bp + (size_t)NTOT * E;        // high-pass spmm output

    // init ego = concat(user_emb, item_emb)
    {
        const long long n4 = (long long)NTOT * E / 4;
        init_ego<<<(int)((n4 + 255) / 256), 256, 0, stream>>>(user_emb, item_emb, A);
    }

    const int spmm_grid = 2048;   // 2048 blocks * 4 waves = 8192 waves (full occupancy)
    for (int k = 0; k < NL; ++k) {
        hipMemsetAsync(Bp, 0, (size_t)2 * NTOT * E * sizeof(float), stream);  // zero Bp+Cd
        spmm_atomic<<<spmm_grid, 256, 0, stream>>>(adj_row, adj_col, adj_val, A, Bp);
        spmm_atomic<<<spmm_grid, 256, 0, stream>>>(hp_row,  hp_col,  hp_val,  A, Cd);
        linear_kernel<<<(NTOT + ROWS_PER_BLOCK - 1) / ROWS_PER_BLOCK, 128, 0, stream>>>(
            Bp, Cd, W + (size_t)k * 2 * E * E, bias + (size_t)k * E, A);
    }

    gather_out<<<(2 * BATCH * E + 255) / 256, 256, 0, stream>>>(A, users, items, out);
}